// Round 1
// baseline (5143.362 us; speedup 1.0000x reference)
//
#include <hip/hip_runtime.h>

#define HW 196
#define WIDTH 14
#define T_STEPS 32
#define KC 64      // centers / GRU channels
#define DD 512     // reduced dim
#define CIN 1024
#define NFR 256    // B*T
#define NB 8       // videos

// ---------------------------------------------------------------------------
// Generic 1x1 conv as tiled GEMM: out[n][m][p] = bias[m] + sum_c W[m][c]*in[n][c][p]
// grid: (pTiles=4, M/64, N). block 256. tile 64m x 64p, CK=16, micro 4x4.
// ---------------------------------------------------------------------------
__global__ __launch_bounds__(256)
void conv1x1_kernel(const float* __restrict__ in, const float* __restrict__ W,
                    const float* __restrict__ bias, float* __restrict__ out,
                    int C, int M) {
  __shared__ float sW[16][68];
  __shared__ float sX[16][68];
  const int tid = threadIdx.x;
  const int tx = tid & 15, ty = tid >> 4;
  const int p0 = blockIdx.x * 64;
  const int m0 = blockIdx.y * 64;
  const int n  = blockIdx.z;
  const float* inN = in + (size_t)n * C * HW;
  float acc[4][4] = {};
  const int wr = tid >> 2;        // m row for W load
  const int wc = (tid & 3) * 4;   // c quad for W load
  const int xc = tid >> 4;        // c row for X load
  const int xq = (tid & 15) * 4;  // p quad for X load

  for (int c0 = 0; c0 < C; c0 += 16) {
    const float* wp = W + (size_t)(m0 + wr) * C + c0 + wc;
    float4 w4 = *reinterpret_cast<const float4*>(wp);
    sW[wc + 0][wr] = w4.x; sW[wc + 1][wr] = w4.y;
    sW[wc + 2][wr] = w4.z; sW[wc + 3][wr] = w4.w;

    const float* xp = inN + (size_t)(c0 + xc) * HW + p0 + xq;
    if (p0 + xq + 3 < HW) {
      *reinterpret_cast<float4*>(&sX[xc][xq]) = *reinterpret_cast<const float4*>(xp);
    } else {
      #pragma unroll
      for (int j = 0; j < 4; ++j)
        sX[xc][xq + j] = (p0 + xq + j < HW) ? xp[j] : 0.0f;
    }
    __syncthreads();
    #pragma unroll
    for (int cc = 0; cc < 16; ++cc) {
      float4 wv = *reinterpret_cast<const float4*>(&sW[cc][ty * 4]);
      float4 xv = *reinterpret_cast<const float4*>(&sX[cc][tx * 4]);
      float wa[4] = {wv.x, wv.y, wv.z, wv.w};
      float xa[4] = {xv.x, xv.y, xv.z, xv.w};
      #pragma unroll
      for (int i = 0; i < 4; ++i)
        #pragma unroll
        for (int j = 0; j < 4; ++j)
          acc[i][j] += wa[i] * xa[j];
    }
    __syncthreads();
  }
  #pragma unroll
  for (int i = 0; i < 4; ++i) {
    int m = m0 + ty * 4 + i;
    float b = bias[m];
    float* op = out + ((size_t)n * M + m) * HW;
    #pragma unroll
    for (int j = 0; j < 4; ++j) {
      int p = p0 + tx * 4 + j;
      if (p < HW) op[p] = acc[i][j] + b;
    }
  }
}

// ---------------------------------------------------------------------------
// GRU phase 1: zpre = conv(h,Uz), rpre = conv(h,Ur); z = sig(wt+zpre) -> zbuf
// rh = sig(wt+rpre)*h -> rhbuf
// grid: (kotile 16 [0..7 -> z, 8..15 -> r], rowhalf 2, chain 16). block 256.
// thread: ko_l = tid>>5 (8), row_l = (tid&31)>>1 (<7), half = tid&1. 7px/thread.
// ---------------------------------------------------------------------------
__global__ __launch_bounds__(256)
void gru_phase1(const float* __restrict__ wxb, const float* __restrict__ Uz,
                const float* __restrict__ Ur, const float* __restrict__ hbuf,
                float* __restrict__ zbuf, float* __restrict__ rhbuf, int t) {
  __shared__ float hp[8][10][16];
  __shared__ float us[8][8][9];
  const int tid = threadIdx.x;
  const int chain = blockIdx.z;
  const int b = chain >> 1, dir = chain & 1;
  const int tw = dir ? (T_STEPS - 1 - t) : t;
  const int ko0 = blockIdx.x * 8;
  const bool is_r = (ko0 >= 64);
  const int k0 = ko0 & 63;
  const int rowbase = blockIdx.y * 7;
  const float* U = is_r ? Ur : Uz;
  const float* hc = hbuf + (size_t)chain * KC * HW;
  const float* wt = wxb + (size_t)(b * T_STEPS + tw) * KC * HW;

  const int ko_l = tid >> 5;
  const int s = tid & 31;
  const int row_l = s >> 1;
  const int half = s & 1;
  const int x0 = half * 7;
  const bool active = (row_l < 7);
  const int orow = rowbase + row_l;

  float acc[7] = {};
  for (int ki0 = 0; ki0 < KC; ki0 += 8) {
    __syncthreads();
    for (int w = tid; w < 1280; w += 256) {
      int ki = w / 160, rem = w - ki * 160;
      int y = rem >> 4, x = rem & 15;
      int srow = rowbase + y - 1, scol = x - 1;
      float v = 0.0f;
      if (srow >= 0 && srow < WIDTH && scol >= 0 && scol < WIDTH)
        v = hc[(ki0 + ki) * HW + srow * WIDTH + scol];
      hp[ki][y][x] = v;
    }
    for (int w = tid; w < 576; w += 256) {
      int ki = w / 72, rem = w - ki * 72;
      int kl = rem / 9, tap = rem - kl * 9;
      us[ki][kl][tap] = U[((size_t)(k0 + kl) * KC + (ki0 + ki)) * 9 + tap];
    }
    __syncthreads();
    if (active) {
      #pragma unroll
      for (int ki = 0; ki < 8; ++ki) {
        float u[9];
        #pragma unroll
        for (int tp = 0; tp < 9; ++tp) u[tp] = us[ki][ko_l][tp];
        #pragma unroll
        for (int dy = 0; dy < 3; ++dy) {
          float hv[9];
          #pragma unroll
          for (int j = 0; j < 9; ++j) hv[j] = hp[ki][row_l + dy][x0 + j];
          #pragma unroll
          for (int xi = 0; xi < 7; ++xi)
            #pragma unroll
            for (int dx = 0; dx < 3; ++dx)
              acc[xi] += u[dy * 3 + dx] * hv[xi + dx];
        }
      }
    }
  }
  if (active) {
    const int k = k0 + ko_l;
    #pragma unroll
    for (int xi = 0; xi < 7; ++xi) {
      int px = orow * WIDTH + x0 + xi;
      float pre = acc[xi] + wt[k * HW + px];
      float sg = 1.0f / (1.0f + expf(-pre));
      if (!is_r) {
        zbuf[(size_t)chain * KC * HW + k * HW + px] = sg;
      } else {
        rhbuf[(size_t)chain * KC * HW + k * HW + px] = sg * hc[k * HW + px];
      }
    }
  }
}

// ---------------------------------------------------------------------------
// GRU phase 2: hh = tanh(wt + conv(rh,Uh)); hnew = (1-z)*hh + z*h; h<-hnew;
// assign[frame] += hnew.   grid: (kotile 8, rowhalf 2, chain 16)
// ---------------------------------------------------------------------------
__global__ __launch_bounds__(256)
void gru_phase2(const float* __restrict__ wxb, const float* __restrict__ Uh,
                float* __restrict__ hbuf, const float* __restrict__ zbuf,
                const float* __restrict__ rhbuf, float* __restrict__ assignb,
                int t) {
  __shared__ float hp[8][10][16];
  __shared__ float us[8][8][9];
  const int tid = threadIdx.x;
  const int chain = blockIdx.z;
  const int b = chain >> 1, dir = chain & 1;
  const int tw = dir ? (T_STEPS - 1 - t) : t;
  const int k0 = blockIdx.x * 8;
  const int rowbase = blockIdx.y * 7;
  const float* rc = rhbuf + (size_t)chain * KC * HW;
  float* hc = hbuf + (size_t)chain * KC * HW;
  const float* zc = zbuf + (size_t)chain * KC * HW;
  const float* wt = wxb + (size_t)(b * T_STEPS + tw) * KC * HW;

  const int ko_l = tid >> 5;
  const int s = tid & 31;
  const int row_l = s >> 1;
  const int half = s & 1;
  const int x0 = half * 7;
  const bool active = (row_l < 7);
  const int orow = rowbase + row_l;

  float acc[7] = {};
  for (int ki0 = 0; ki0 < KC; ki0 += 8) {
    __syncthreads();
    for (int w = tid; w < 1280; w += 256) {
      int ki = w / 160, rem = w - ki * 160;
      int y = rem >> 4, x = rem & 15;
      int srow = rowbase + y - 1, scol = x - 1;
      float v = 0.0f;
      if (srow >= 0 && srow < WIDTH && scol >= 0 && scol < WIDTH)
        v = rc[(ki0 + ki) * HW + srow * WIDTH + scol];
      hp[ki][y][x] = v;
    }
    for (int w = tid; w < 576; w += 256) {
      int ki = w / 72, rem = w - ki * 72;
      int kl = rem / 9, tap = rem - kl * 9;
      us[ki][kl][tap] = Uh[((size_t)(k0 + kl) * KC + (ki0 + ki)) * 9 + tap];
    }
    __syncthreads();
    if (active) {
      #pragma unroll
      for (int ki = 0; ki < 8; ++ki) {
        float u[9];
        #pragma unroll
        for (int tp = 0; tp < 9; ++tp) u[tp] = us[ki][ko_l][tp];
        #pragma unroll
        for (int dy = 0; dy < 3; ++dy) {
          float hv[9];
          #pragma unroll
          for (int j = 0; j < 9; ++j) hv[j] = hp[ki][row_l + dy][x0 + j];
          #pragma unroll
          for (int xi = 0; xi < 7; ++xi)
            #pragma unroll
            for (int dx = 0; dx < 3; ++dx)
              acc[xi] += u[dy * 3 + dx] * hv[xi + dx];
        }
      }
    }
  }
  if (active) {
    const int k = k0 + ko_l;
    #pragma unroll
    for (int xi = 0; xi < 7; ++xi) {
      int px = orow * WIDTH + x0 + xi;
      float pre = acc[xi] + wt[k * HW + px];
      float hh = tanhf(pre);
      float zv = zc[k * HW + px];
      float ho = hc[k * HW + px];
      float hn = (1.0f - zv) * hh + zv * ho;
      hc[k * HW + px] = hn;
      assignb[((size_t)(b * T_STEPS + tw) * KC + k) * HW + px] += hn;
    }
  }
}

// ---------------------------------------------------------------------------
// softmax over K=64 per (n,px) column, in place. grid 196 x 256 threads.
// ---------------------------------------------------------------------------
__global__ __launch_bounds__(256)
void softmax_kernel(float* __restrict__ a) {
  int idx = blockIdx.x * 256 + threadIdx.x;   // 0..50175
  int n = idx / HW, px = idx - n * HW;
  float* col = a + (size_t)n * KC * HW + px;
  float v[KC];
  float mx = -3.4e38f;
  #pragma unroll
  for (int k = 0; k < KC; ++k) { v[k] = col[k * HW]; mx = fmaxf(mx, v[k]); }
  float ssum = 0.0f;
  #pragma unroll
  for (int k = 0; k < KC; ++k) { v[k] = expf(v[k] - mx); ssum += v[k]; }
  float inv = 1.0f / ssum;
  #pragma unroll
  for (int k = 0; k < KC; ++k) col[k * HW] = v[k] * inv;
}

// ---------------------------------------------------------------------------
// S[b][k] = sum over (t,p) of assign. grid (64,8), block 256.
// ---------------------------------------------------------------------------
__global__ __launch_bounds__(256)
void sreduce_kernel(const float* __restrict__ a, float* __restrict__ S) {
  __shared__ float red[256];
  const int k = blockIdx.x, b = blockIdx.y, tid = threadIdx.x;
  const float* base = a + ((size_t)b * T_STEPS * KC + k) * HW;
  float sum = 0.0f;
  for (int i = tid; i < T_STEPS * HW; i += 256) {
    int t = i / HW, p = i - t * HW;
    sum += base[(size_t)t * KC * HW + p];
  }
  red[tid] = sum; __syncthreads();
  for (int st = 128; st > 0; st >>= 1) {
    if (tid < st) red[tid] += red[tid + st];
    __syncthreads();
  }
  if (tid == 0) S[b * KC + k] = red[0];
}

// ---------------------------------------------------------------------------
// VLAD GEMM partials: Gpart[tc][b][k][d] = sum over t in chunk, p of
//   assign[b*32+t][k][p] * xr[b*32+t][d][p].
// grid (dtile=8, tc=4, b=8). block 256. tile 64k x 64d. micro 4x4.
// ---------------------------------------------------------------------------
__global__ __launch_bounds__(256)
void vlad_gemm_kernel(const float* __restrict__ a, const float* __restrict__ xr,
                      float* __restrict__ Gpart) {
  __shared__ float sA[16][68];
  __shared__ float sX[16][68];
  const int tid = threadIdx.x;
  const int tx = tid & 15, ty = tid >> 4;
  const int d0 = blockIdx.x * 64;
  const int tc = blockIdx.y;
  const int b  = blockIdx.z;
  const int lr = tid >> 2;        // row (k or d) for loads
  const int pq = (tid & 3) * 4;   // p quad
  float acc[4][4] = {};

  for (int tt = 0; tt < 8; ++tt) {
    int n = b * T_STEPS + tc * 8 + tt;
    const float* an = a + (size_t)n * KC * HW;
    const float* xn = xr + (size_t)n * DD * HW;
    for (int p0 = 0; p0 < HW; p0 += 16) {
      __syncthreads();
      #pragma unroll
      for (int j = 0; j < 4; ++j) {
        int p = p0 + pq + j;
        sA[pq + j][lr] = (p < HW) ? an[lr * HW + p] : 0.0f;
        sX[pq + j][lr] = (p < HW) ? xn[(d0 + lr) * HW + p] : 0.0f;
      }
      __syncthreads();
      #pragma unroll
      for (int pp = 0; pp < 16; ++pp) {
        float4 av = *reinterpret_cast<const float4*>(&sA[pp][ty * 4]);
        float4 xv = *reinterpret_cast<const float4*>(&sX[pp][tx * 4]);
        float aa[4] = {av.x, av.y, av.z, av.w};
        float xx[4] = {xv.x, xv.y, xv.z, xv.w};
        #pragma unroll
        for (int i = 0; i < 4; ++i)
          #pragma unroll
          for (int j = 0; j < 4; ++j)
            acc[i][j] += aa[i] * xx[j];
      }
    }
  }
  float* gp = Gpart + ((size_t)(tc * NB + b) * KC) * DD;
  #pragma unroll
  for (int i = 0; i < 4; ++i)
    #pragma unroll
    for (int j = 0; j < 4; ++j)
      gp[(ty * 4 + i) * DD + d0 + tx * 4 + j] = acc[i][j];
}

// ---------------------------------------------------------------------------
// finalize1: vlad = sum_tc Gpart - S*centers; intra-norm per (b,k); write out;
// accumulate per-b sum of squares (post-intra-norm). grid (64,8), block 256.
// ---------------------------------------------------------------------------
__global__ __launch_bounds__(256)
void finalize1_kernel(const float* __restrict__ Gpart, const float* __restrict__ S,
                      const float* __restrict__ centers, float* __restrict__ out,
                      float* __restrict__ bsum) {
  __shared__ float red[256];
  const int k = blockIdx.x, b = blockIdx.y, tid = threadIdx.x;
  const float sv = S[b * KC + k];
  float vals[2];
  float ss = 0.0f;
  #pragma unroll
  for (int r = 0; r < 2; ++r) {
    int d = tid + r * 256;
    float g = 0.0f;
    #pragma unroll
    for (int tc = 0; tc < 4; ++tc)
      g += Gpart[((size_t)(tc * NB + b) * KC + k) * DD + d];
    float v = g - sv * centers[k * DD + d];
    vals[r] = v; ss += v * v;
  }
  red[tid] = ss; __syncthreads();
  for (int st = 128; st > 0; st >>= 1) {
    if (tid < st) red[tid] += red[tid + st];
    __syncthreads();
  }
  float tot = red[0];
  float inv = 1.0f / fmaxf(sqrtf(tot), 1e-12f);
  #pragma unroll
  for (int r = 0; r < 2; ++r) {
    int d = tid + r * 256;
    out[(size_t)b * KC * DD + k * DD + d] = vals[r] * inv;
  }
  if (tid == 0) atomicAdd(&bsum[b], tot * inv * inv);
}

__global__ __launch_bounds__(256)
void finalize2_kernel(float* __restrict__ out, const float* __restrict__ bsum) {
  int idx = blockIdx.x * 256 + threadIdx.x;  // 262144
  int b = idx >> 15;
  out[idx] = out[idx] / fmaxf(sqrtf(bsum[b]), 1e-12f);
}

// ---------------------------------------------------------------------------
extern "C" void kernel_launch(void* const* d_in, const int* in_sizes, int n_in,
                              void* d_out, int out_size, void* d_ws, size_t ws_size,
                              hipStream_t stream) {
  const float* x       = (const float*)d_in[0];
  const float* redu_w  = (const float*)d_in[1];
  const float* redu_b  = (const float*)d_in[2];
  const float* share_w = (const float*)d_in[3];
  const float* share_b = (const float*)d_in[4];
  const float* Uz      = (const float*)d_in[5];
  const float* Ur      = (const float*)d_in[6];
  const float* Uh      = (const float*)d_in[7];
  const float* centers = (const float*)d_in[8];
  float* out = (float*)d_out;

  float* xr     = (float*)d_ws;                       // 256*512*196
  float* wxb    = xr     + (size_t)NFR * DD * HW;     // 256*64*196
  float* assignb= wxb    + (size_t)NFR * KC * HW;     // 256*64*196
  float* hbuf   = assignb+ (size_t)NFR * KC * HW;     // 16*64*196
  float* zbuf   = hbuf   + (size_t)16 * KC * HW;
  float* rhbuf  = zbuf   + (size_t)16 * KC * HW;
  float* Gpart  = rhbuf  + (size_t)16 * KC * HW;      // 4*8*64*512
  float* S      = Gpart  + (size_t)4 * NB * KC * DD;  // 512
  float* bsum   = S      + 512;                       // 8

  hipMemsetAsync(assignb, 0, (size_t)NFR * KC * HW * sizeof(float), stream);
  hipMemsetAsync(hbuf, 0, (size_t)16 * KC * HW * sizeof(float), stream);
  hipMemsetAsync(bsum, 0, NB * sizeof(float), stream);

  // stage A: 1024 -> 512 reduction conv
  conv1x1_kernel<<<dim3(4, 8, NFR), 256, 0, stream>>>(x, redu_w, redu_b, xr, CIN, DD);
  // stage B: 512 -> 64 share conv
  conv1x1_kernel<<<dim3(4, 1, NFR), 256, 0, stream>>>(xr, share_w, share_b, wxb, DD, KC);

  // GRU recurrence: fwd(dir0) and bwd(dir1) chains concurrently
  for (int t = 0; t < T_STEPS; ++t) {
    gru_phase1<<<dim3(16, 2, 16), 256, 0, stream>>>(wxb, Uz, Ur, hbuf, zbuf, rhbuf, t);
    gru_phase2<<<dim3(8, 2, 16), 256, 0, stream>>>(wxb, Uh, hbuf, zbuf, rhbuf, assignb, t);
  }

  softmax_kernel<<<dim3(196), 256, 0, stream>>>(assignb);
  sreduce_kernel<<<dim3(64, 8), 256, 0, stream>>>(assignb, S);
  vlad_gemm_kernel<<<dim3(8, 4, 8), 256, 0, stream>>>(assignb, xr, Gpart);
  finalize1_kernel<<<dim3(64, 8), 256, 0, stream>>>(Gpart, S, centers, out, bsum);
  finalize2_kernel<<<dim3(1024), 256, 0, stream>>>(out, bsum);
}